// Round 1
// baseline (290.187 us; speedup 1.0000x reference)
//
#include <hip/hip_runtime.h>

#define BATCH 128
#define VIS   98
#define TOK   196
#define TOK2  392
#define ENC   1024
#define DEC   512
#define MSK   294   // 2*TOK - VIS

typedef __bf16 bf16x8 __attribute__((ext_vector_type(8)));
typedef float  f32x4  __attribute__((ext_vector_type(4)));

__device__ __forceinline__ unsigned short f2bf(float f) {
    union { float f; unsigned u; } c; c.f = f;
    unsigned u = c.u;
    return (unsigned short)((u + 0x7fffu + ((u >> 16) & 1u)) >> 16);
}

// fp32 -> bf16 elementwise (float4 / ushort4 vectorized)
__global__ __launch_bounds__(256) void cvt_bf16(const float* __restrict__ src,
                                                unsigned short* __restrict__ dst,
                                                int n4) {
    int i = blockIdx.x * 256 + threadIdx.x;
    if (i >= n4) return;
    float4 f = ((const float4*)src)[i];
    ushort4 o;
    o.x = f2bf(f.x); o.y = f2bf(f.y); o.z = f2bf(f.z); o.w = f2bf(f.w);
    ((ushort4*)dst)[i] = o;
}

// Per batch row: visibility flags + sorted complement of masked_ids via ballot scan.
__global__ __launch_bounds__(512) void build_map(const int* __restrict__ mids,
                                                 int* __restrict__ visids,
                                                 unsigned char* __restrict__ flags) {
    int b = blockIdx.x;
    __shared__ unsigned char lf[TOK2];
    __shared__ int wtot[8];
    int tid = threadIdx.x;
    if (tid < TOK2) lf[tid] = 1;
    __syncthreads();
    if (tid < MSK) lf[mids[b * MSK + tid]] = 0;
    __syncthreads();
    int flag = (tid < TOK2) ? (int)lf[tid] : 0;
    unsigned long long bal = __ballot(flag != 0);
    int lane = tid & 63, wv = tid >> 6;
    int pre = __popcll(bal & ((1ull << lane) - 1ull));
    if (lane == 0) wtot[wv] = __popcll(bal);
    __syncthreads();
    int off = 0;
    for (int i = 0; i < wv; ++i) off += wtot[i];
    if (flag) visids[b * VIS + off + pre] = tid;   // stable: ascending token id
    if (tid < TOK2) flags[b * TOK2 + tid] = lf[tid];
}

// masked slots: out = mask_token + pos + view_embed
__global__ __launch_bounds__(256) void fill_masked(const unsigned char* __restrict__ flags,
                                                   const float* __restrict__ mask_token,
                                                   const float* __restrict__ pos,
                                                   const float* __restrict__ ve,
                                                   float* __restrict__ out) {
    int b = blockIdx.y;
    int g = blockIdx.x * 256 + threadIdx.x;   // over TOK2*128 float4 slots
    int t  = g >> 7;
    int d4 = g & 127;
    int tok = b * TOK2 + t;
    if (flags[tok]) return;                   // visible -> written by gemm_scatter
    float4 m = ((const float4*)mask_token)[d4];
    float4 p = ((const float4*)(pos + (size_t)t * DEC))[d4];
    float4 v = ((const float4*)(ve + (t >= TOK ? DEC : 0)))[d4];
    float4 r;
    r.x = m.x + p.x + v.x;
    r.y = m.y + p.y + v.y;
    r.z = m.z + p.z + v.z;
    r.w = m.w + p.w + v.w;
    ((float4*)(out + (size_t)tok * DEC))[d4] = r;
}

// xp = x @ W^T + bias, scattered to out[b, visids[b,v], :] (+pos +ve).
// Block = 256 thr (4 waves). Block tile: 64 rows x 64 cols; wave w: rows [w*16, w*16+16).
// mfma_f32_16x16x32_bf16: A lane(l): row=l&15, k=(l>>4)*8+j ; B lane: col=l&15, same k;
// D lane: col=l&15, row=(l>>4)*4+reg   [m89-verified layout]
__global__ __launch_bounds__(256) void gemm_scatter(
    const unsigned short* __restrict__ xb,   // (B*V, ENC) bf16 bits
    const unsigned short* __restrict__ wb,   // (DEC, ENC) bf16 bits
    const float* __restrict__ bias,
    const float* __restrict__ pos,
    const float* __restrict__ ve,
    const int* __restrict__ vis,             // (B*V) -> t
    float* __restrict__ out) {
    int m0 = blockIdx.x * 64;
    int n0 = blockIdx.y * 64;
    int tid = threadIdx.x;
    int w = tid >> 6, lane = tid & 63;
    int l16 = lane & 15, quad = lane >> 4;

    __shared__ int rowdst[64];   // b*392 + t
    __shared__ int rowt[64];     // t
    if (tid < 64) {
        int gr = m0 + tid;       // global row in [0, B*V)
        int bb = gr / VIS;
        int t  = vis[gr];
        rowt[tid] = t;
        rowdst[tid] = bb * TOK2 + t;
    }
    __syncthreads();

    const unsigned short* xrow = xb + (size_t)(m0 + w * 16 + l16) * ENC + quad * 8;
    const unsigned short* wr0  = wb + (size_t)(n0 +  0 + l16) * ENC + quad * 8;
    const unsigned short* wr1  = wb + (size_t)(n0 + 16 + l16) * ENC + quad * 8;
    const unsigned short* wr2  = wb + (size_t)(n0 + 32 + l16) * ENC + quad * 8;
    const unsigned short* wr3  = wb + (size_t)(n0 + 48 + l16) * ENC + quad * 8;

    f32x4 acc0 = {0.f, 0.f, 0.f, 0.f};
    f32x4 acc1 = {0.f, 0.f, 0.f, 0.f};
    f32x4 acc2 = {0.f, 0.f, 0.f, 0.f};
    f32x4 acc3 = {0.f, 0.f, 0.f, 0.f};

    for (int k = 0; k < ENC; k += 32) {
        bf16x8 a  = *(const bf16x8*)(const void*)(xrow + k);
        bf16x8 b0 = *(const bf16x8*)(const void*)(wr0 + k);
        bf16x8 b1 = *(const bf16x8*)(const void*)(wr1 + k);
        bf16x8 b2 = *(const bf16x8*)(const void*)(wr2 + k);
        bf16x8 b3 = *(const bf16x8*)(const void*)(wr3 + k);
        acc0 = __builtin_amdgcn_mfma_f32_16x16x32_bf16(a, b0, acc0, 0, 0, 0);
        acc1 = __builtin_amdgcn_mfma_f32_16x16x32_bf16(a, b1, acc1, 0, 0, 0);
        acc2 = __builtin_amdgcn_mfma_f32_16x16x32_bf16(a, b2, acc2, 0, 0, 0);
        acc3 = __builtin_amdgcn_mfma_f32_16x16x32_bf16(a, b3, acc3, 0, 0, 0);
    }

    f32x4 accs[4] = {acc0, acc1, acc2, acc3};
    for (int nt = 0; nt < 4; ++nt) {
        int col = n0 + nt * 16 + l16;
        float bc = bias[col];
        for (int r = 0; r < 4; ++r) {
            int rl = w * 16 + quad * 4 + r;
            int t = rowt[rl];
            float val = accs[nt][r] + bc
                      + pos[(size_t)t * DEC + col]
                      + ve[(t >= TOK ? DEC : 0) + col];
            out[(size_t)rowdst[rl] * DEC + col] = val;
        }
    }
}

extern "C" void kernel_launch(void* const* d_in, const int* in_sizes, int n_in,
                              void* d_out, int out_size, void* d_ws, size_t ws_size,
                              hipStream_t stream) {
    (void)in_sizes; (void)n_in; (void)out_size; (void)ws_size;
    const float* x    = (const float*)d_in[0];
    const int*   mids = (const int*)d_in[1];
    const float* W    = (const float*)d_in[2];
    const float* bias = (const float*)d_in[3];
    const float* mt   = (const float*)d_in[4];
    const float* pos  = (const float*)d_in[5];
    const float* ve   = (const float*)d_in[6];
    float* out = (float*)d_out;

    // workspace layout (bf16 staging + maps), ~26.9 MB total
    unsigned short* xb = (unsigned short*)d_ws;                      // B*V*ENC bf16
    unsigned short* wbm = xb + (size_t)BATCH * VIS * ENC;            // DEC*ENC bf16
    int* visids = (int*)(wbm + (size_t)DEC * ENC);                   // B*V int
    unsigned char* flags = (unsigned char*)(visids + BATCH * VIS);   // B*392 bytes

    int n4x = BATCH * VIS * ENC / 4;
    hipLaunchKernelGGL(cvt_bf16, dim3((n4x + 255) / 256), dim3(256), 0, stream, x, xb, n4x);
    int n4w = DEC * ENC / 4;
    hipLaunchKernelGGL(cvt_bf16, dim3((n4w + 255) / 256), dim3(256), 0, stream, W, wbm, n4w);
    hipLaunchKernelGGL(build_map, dim3(BATCH), dim3(512), 0, stream, mids, visids, flags);
    hipLaunchKernelGGL(fill_masked, dim3(TOK2 * 128 / 256, BATCH), dim3(256), 0, stream,
                       flags, mt, pos, ve, out);
    hipLaunchKernelGGL(gemm_scatter, dim3((BATCH * VIS) / 64, DEC / 64), dim3(256), 0, stream,
                       xb, wbm, bias, pos, ve, visids, out);
}

// Round 2
// 235.915 us; speedup vs baseline: 1.2300x; 1.2300x over previous
//
#include <hip/hip_runtime.h>

#define BATCH 128
#define VIS   98
#define TOK   196
#define TOK2  392
#define ENC   1024
#define DEC   512
#define MSK   294   // 2*TOK - VIS

typedef __bf16 bf16x8 __attribute__((ext_vector_type(8)));
typedef float  f32x4  __attribute__((ext_vector_type(4)));

__device__ __forceinline__ unsigned short f2bf(float f) {
    union { float f; unsigned u; } c; c.f = f;
    unsigned u = c.u;
    return (unsigned short)((u + 0x7fffu + ((u >> 16) & 1u)) >> 16);
}

__device__ __forceinline__ bf16x8 cvt8(f32x4 lo, f32x4 hi) {
    union { unsigned short u[8]; bf16x8 v; } r;
    r.u[0] = f2bf(lo[0]); r.u[1] = f2bf(lo[1]); r.u[2] = f2bf(lo[2]); r.u[3] = f2bf(lo[3]);
    r.u[4] = f2bf(hi[0]); r.u[5] = f2bf(hi[1]); r.u[6] = f2bf(hi[2]); r.u[7] = f2bf(hi[3]);
    return r.v;
}

// fp32 -> bf16 elementwise (float4 / ushort4 vectorized) — used for W only
__global__ __launch_bounds__(256) void cvt_bf16(const float* __restrict__ src,
                                                unsigned short* __restrict__ dst,
                                                int n4) {
    int i = blockIdx.x * 256 + threadIdx.x;
    if (i >= n4) return;
    float4 f = ((const float4*)src)[i];
    ushort4 o;
    o.x = f2bf(f.x); o.y = f2bf(f.y); o.z = f2bf(f.z); o.w = f2bf(f.w);
    ((ushort4*)dst)[i] = o;
}

// Per batch row: visibility flags + sorted complement of masked_ids via ballot scan.
__global__ __launch_bounds__(512) void build_map(const int* __restrict__ mids,
                                                 int* __restrict__ visids,
                                                 unsigned char* __restrict__ flags) {
    int b = blockIdx.x;
    __shared__ unsigned char lf[TOK2];
    __shared__ int wtot[8];
    int tid = threadIdx.x;
    if (tid < TOK2) lf[tid] = 1;
    __syncthreads();
    if (tid < MSK) lf[mids[b * MSK + tid]] = 0;
    __syncthreads();
    int flag = (tid < TOK2) ? (int)lf[tid] : 0;
    unsigned long long bal = __ballot(flag != 0);
    int lane = tid & 63, wv = tid >> 6;
    int pre = __popcll(bal & ((1ull << lane) - 1ull));
    if (lane == 0) wtot[wv] = __popcll(bal);
    __syncthreads();
    int off = 0;
    for (int i = 0; i < wv; ++i) off += wtot[i];
    if (flag) visids[b * VIS + off + pre] = tid;   // stable: ascending token id
    if (tid < TOK2) flags[b * TOK2 + tid] = lf[tid];
}

// masked slots: out = mask_token + pos + view_embed
__global__ __launch_bounds__(256) void fill_masked(const unsigned char* __restrict__ flags,
                                                   const float* __restrict__ mask_token,
                                                   const float* __restrict__ pos,
                                                   const float* __restrict__ ve,
                                                   float* __restrict__ out) {
    int b = blockIdx.y;
    int g = blockIdx.x * 256 + threadIdx.x;   // over TOK2*128 float4 slots
    int t  = g >> 7;
    int d4 = g & 127;
    int tok = b * TOK2 + t;
    if (flags[tok]) return;                   // visible -> written by gemm_scatter
    float4 m = ((const float4*)mask_token)[d4];
    float4 p = ((const float4*)(pos + (size_t)t * DEC))[d4];
    float4 v = ((const float4*)(ve + (t >= TOK ? DEC : 0)))[d4];
    float4 r;
    r.x = m.x + p.x + v.x;
    r.y = m.y + p.y + v.y;
    r.z = m.z + p.z + v.z;
    r.w = m.w + p.w + v.w;
    ((float4*)(out + (size_t)tok * DEC))[d4] = r;
}

// xp = x @ W^T + bias, scattered to out[b, visids[b,v], :] (+pos +ve).
// Block = 256 thr (4 waves). Block tile: 32 rows x 512 cols (FULL N -> x read once).
// Wave w handles cols [128w, 128w+128): 2 mtiles x 8 ntiles, 16 MFMAs per k32-step.
// Explicit double-buffered register prefetch: loads for step s+1 issued before MFMAs of s.
// mfma_f32_16x16x32_bf16: A lane: row=l&15, k=(l>>4)*8+j ; B lane: col=l&15, same k;
// D lane: col=l&15, row=(l>>4)*4+reg   [m89-verified layout]
__global__ __launch_bounds__(256, 2) void gemm_scatter(
    const float* __restrict__ x,             // (B*V, ENC) fp32
    const unsigned short* __restrict__ wb,   // (DEC, ENC) bf16 bits
    const float* __restrict__ bias,
    const float* __restrict__ pos,
    const float* __restrict__ ve,
    const int* __restrict__ vis,             // (B*V) -> t
    float* __restrict__ out) {
    int m0 = blockIdx.x * 32;
    int tid = threadIdx.x;
    int w = tid >> 6, lane = tid & 63;
    int l16 = lane & 15, quad = lane >> 4;

    __shared__ int rowdst[32];   // b*392 + t
    __shared__ int rowt[32];     // t
    if (tid < 32) {
        int gr = m0 + tid;       // global row in [0, B*V)
        int bb = gr / VIS;
        int t  = vis[gr];
        rowt[tid] = t;
        rowdst[tid] = bb * TOK2 + t;
    }
    __syncthreads();

    const float* ap = x + (size_t)(m0 + l16) * ENC + quad * 8;
    const unsigned short* bp = wb + (size_t)(w * 128 + l16) * ENC + quad * 8;

    f32x4 acc[2][8];
    #pragma unroll
    for (int i = 0; i < 2; ++i)
        #pragma unroll
        for (int j = 0; j < 8; ++j)
            acc[i][j] = (f32x4){0.f, 0.f, 0.f, 0.f};

    f32x4  af[2][2][2];   // [buf][mtile][half]
    bf16x8 bfr[2][8];     // [buf][ntile]

    // preload step 0
    #pragma unroll
    for (int i = 0; i < 2; ++i) {
        af[0][i][0] = *(const f32x4*)(ap + (size_t)i * 16 * ENC);
        af[0][i][1] = *(const f32x4*)(ap + (size_t)i * 16 * ENC + 4);
    }
    #pragma unroll
    for (int j = 0; j < 8; ++j)
        bfr[0][j] = *(const bf16x8*)(const void*)(bp + (size_t)j * 16 * ENC);

    #pragma unroll
    for (int s = 0; s < 32; ++s) {
        int cb = s & 1, nb = cb ^ 1;
        if (s < 31) {
            int k = (s + 1) * 32;
            #pragma unroll
            for (int i = 0; i < 2; ++i) {
                af[nb][i][0] = *(const f32x4*)(ap + (size_t)i * 16 * ENC + k);
                af[nb][i][1] = *(const f32x4*)(ap + (size_t)i * 16 * ENC + k + 4);
            }
            #pragma unroll
            for (int j = 0; j < 8; ++j)
                bfr[nb][j] = *(const bf16x8*)(const void*)(bp + (size_t)j * 16 * ENC + k);
        }
        bf16x8 ab[2];
        ab[0] = cvt8(af[cb][0][0], af[cb][0][1]);
        ab[1] = cvt8(af[cb][1][0], af[cb][1][1]);
        #pragma unroll
        for (int j = 0; j < 8; ++j) {
            acc[0][j] = __builtin_amdgcn_mfma_f32_16x16x32_bf16(ab[0], bfr[cb][j], acc[0][j], 0, 0, 0);
            acc[1][j] = __builtin_amdgcn_mfma_f32_16x16x32_bf16(ab[1], bfr[cb][j], acc[1][j], 0, 0, 0);
        }
    }

    #pragma unroll
    for (int i = 0; i < 2; ++i)
        #pragma unroll
        for (int j = 0; j < 8; ++j) {
            int col = w * 128 + j * 16 + l16;
            float bc = bias[col];
            #pragma unroll
            for (int r = 0; r < 4; ++r) {
                int rl = i * 16 + quad * 4 + r;
                int t = rowt[rl];
                out[(size_t)rowdst[rl] * DEC + col] = acc[i][j][r] + bc
                    + pos[(size_t)t * DEC + col]
                    + ve[(t >= TOK ? DEC : 0) + col];
            }
        }
}

extern "C" void kernel_launch(void* const* d_in, const int* in_sizes, int n_in,
                              void* d_out, int out_size, void* d_ws, size_t ws_size,
                              hipStream_t stream) {
    (void)in_sizes; (void)n_in; (void)out_size; (void)ws_size;
    const float* x    = (const float*)d_in[0];
    const int*   mids = (const int*)d_in[1];
    const float* W    = (const float*)d_in[2];
    const float* bias = (const float*)d_in[3];
    const float* mt   = (const float*)d_in[4];
    const float* pos  = (const float*)d_in[5];
    const float* ve   = (const float*)d_in[6];
    float* out = (float*)d_out;

    // workspace: W bf16 (1 MB) + maps
    unsigned short* wbm = (unsigned short*)d_ws;                     // DEC*ENC bf16
    int* visids = (int*)(wbm + (size_t)DEC * ENC);                   // B*V int
    unsigned char* flags = (unsigned char*)(visids + BATCH * VIS);   // B*392 bytes

    int n4w = DEC * ENC / 4;
    hipLaunchKernelGGL(cvt_bf16, dim3((n4w + 255) / 256), dim3(256), 0, stream, W, wbm, n4w);
    hipLaunchKernelGGL(build_map, dim3(BATCH), dim3(512), 0, stream, mids, visids, flags);
    hipLaunchKernelGGL(fill_masked, dim3(TOK2 * 128 / 256, BATCH), dim3(256), 0, stream,
                       flags, mt, pos, ve, out);
    hipLaunchKernelGGL(gemm_scatter, dim3((BATCH * VIS) / 32), dim3(256), 0, stream,
                       x, wbm, bias, pos, ve, visids, out);
}

// Round 3
// 189.436 us; speedup vs baseline: 1.5318x; 1.2454x over previous
//
#include <hip/hip_runtime.h>

#define BATCH 128
#define VIS   98
#define TOK   196
#define TOK2  392
#define ENC   1024
#define DEC   512
#define MSK   294   // 2*TOK - VIS

typedef __bf16 bf16x8 __attribute__((ext_vector_type(8)));
typedef float  f32x4  __attribute__((ext_vector_type(4)));

__device__ __forceinline__ unsigned short f2bf(float f) {
    union { float f; unsigned u; } c; c.f = f;
    unsigned u = c.u;
    return (unsigned short)((u + 0x7fffu + ((u >> 16) & 1u)) >> 16);
}

__device__ __forceinline__ bf16x8 cvt8(f32x4 lo, f32x4 hi) {
    union { unsigned short u[8]; bf16x8 v; } r;
    r.u[0] = f2bf(lo[0]); r.u[1] = f2bf(lo[1]); r.u[2] = f2bf(lo[2]); r.u[3] = f2bf(lo[3]);
    r.u[4] = f2bf(hi[0]); r.u[5] = f2bf(hi[1]); r.u[6] = f2bf(hi[2]); r.u[7] = f2bf(hi[3]);
    return r.v;
}

// async global -> LDS, 16 B per lane; LDS dest must be wave-uniform base + lane*16
__device__ __forceinline__ void g2lds16(const void* gptr, void* lptr) {
    __builtin_amdgcn_global_load_lds(
        (const __attribute__((address_space(1))) void*)gptr,
        (__attribute__((address_space(3))) void*)lptr, 16, 0, 0);
}

// fp32 -> bf16 elementwise — used for W only
__global__ __launch_bounds__(256) void cvt_bf16(const float* __restrict__ src,
                                                unsigned short* __restrict__ dst,
                                                int n4) {
    int i = blockIdx.x * 256 + threadIdx.x;
    if (i >= n4) return;
    float4 f = ((const float4*)src)[i];
    ushort4 o;
    o.x = f2bf(f.x); o.y = f2bf(f.y); o.z = f2bf(f.z); o.w = f2bf(f.w);
    ((ushort4*)dst)[i] = o;
}

// Per batch row: visibility flags + sorted complement of masked_ids via ballot scan.
__global__ __launch_bounds__(512) void build_map(const int* __restrict__ mids,
                                                 int* __restrict__ visids,
                                                 unsigned char* __restrict__ flags) {
    int b = blockIdx.x;
    __shared__ unsigned char lf[TOK2];
    __shared__ int wtot[8];
    int tid = threadIdx.x;
    if (tid < TOK2) lf[tid] = 1;
    __syncthreads();
    if (tid < MSK) lf[mids[b * MSK + tid]] = 0;
    __syncthreads();
    int flag = (tid < TOK2) ? (int)lf[tid] : 0;
    unsigned long long bal = __ballot(flag != 0);
    int lane = tid & 63, wv = tid >> 6;
    int pre = __popcll(bal & ((1ull << lane) - 1ull));
    if (lane == 0) wtot[wv] = __popcll(bal);
    __syncthreads();
    int off = 0;
    for (int i = 0; i < wv; ++i) off += wtot[i];
    if (flag) visids[b * VIS + off + pre] = tid;   // stable: ascending token id
    if (tid < TOK2) flags[b * TOK2 + tid] = lf[tid];
}

// masked slots: out = mask_token + pos + view_embed
__global__ __launch_bounds__(256) void fill_masked(const unsigned char* __restrict__ flags,
                                                   const float* __restrict__ mask_token,
                                                   const float* __restrict__ pos,
                                                   const float* __restrict__ ve,
                                                   float* __restrict__ out) {
    int b = blockIdx.y;
    int g = blockIdx.x * 256 + threadIdx.x;   // over TOK2*128 float4 slots
    int t  = g >> 7;
    int d4 = g & 127;
    int tok = b * TOK2 + t;
    if (flags[tok]) return;                   // visible -> written by gemm_scatter
    float4 m = ((const float4*)mask_token)[d4];
    float4 p = ((const float4*)(pos + (size_t)t * DEC))[d4];
    float4 v = ((const float4*)(ve + (t >= TOK ? DEC : 0)))[d4];
    float4 r;
    r.x = m.x + p.x + v.x;
    r.y = m.y + p.y + v.y;
    r.z = m.z + p.z + v.z;
    r.w = m.w + p.w + v.w;
    ((float4*)(out + (size_t)tok * DEC))[d4] = r;
}

// xp = x @ W^T + bias, scattered to out[b, visids[b,v], :] (+pos +ve).
// m97 structure: 128x128 tile, BK=64, 256 thr (4 waves, 2x2), global_load_lds staging.
// A kept fp32 in LDS (converted to bf16 at fragment read); B bf16.
// XOR chunk swizzle: LDS chunk position p = c ^ (row % nchunks) -> conflict-free ds_read_b128
// while keeping LDS dest = base + lane*16 for global_load_lds (global src permuted per lane).
// mfma_f32_16x16x32_bf16: A lane: row=l&15, k=(l>>4)*8+j ; B lane: col=l&15, same k;
// D lane: col=l&15, row=(l>>4)*4+reg   [m89-verified layout]
__global__ __launch_bounds__(256, 2) void gemm_scatter(
    const float* __restrict__ x,             // (B*V, ENC) fp32
    const unsigned short* __restrict__ wb,   // (DEC, ENC) bf16 bits
    const float* __restrict__ bias,
    const float* __restrict__ pos,
    const float* __restrict__ ve,
    const int* __restrict__ vis,             // (B*V) -> t
    float* __restrict__ out) {
    __shared__ float          As[128 * 64];          // 32 KB, chunks [m][p], p = c ^ (m&15)
    __shared__ unsigned short Bs[128 * 64];          // 16 KB, chunks [n][p], p = c ^ (n&7)
    __shared__ int rowdst[128];
    __shared__ int rowt[128];

    int tid = threadIdx.x;
    int lane = tid & 63, w = tid >> 6;
    int l16 = lane & 15, q = lane >> 4;
    int wm = w & 1, wn = w >> 1;
    int m0 = blockIdx.y * 128, n0 = blockIdx.x * 128;

    if (tid < 128) {
        int gr = m0 + tid;
        int t = vis[gr];
        rowt[tid] = t;
        rowdst[tid] = (gr / VIS) * TOK2 + t;
    }

    // staging source pointers (XOR-permuted chunk within each row -> still coalesced)
    int cA = (tid & 15) ^ ((tid >> 4) & 15);         // A: 16 chunks/row (256 B fp32)
    const float* gA = x + (size_t)(m0 + (tid >> 4)) * ENC + cA * 4;
    int cB = (tid & 7) ^ ((tid >> 3) & 7);           // B: 8 chunks/row (128 B bf16)
    const unsigned short* gB = wb + (size_t)(n0 + (tid >> 3)) * ENC + cB * 8;
    char* ldsA = (char*)As + tid * 16;
    char* ldsB = (char*)Bs + tid * 16;

    f32x4 acc[4][4];
    #pragma unroll
    for (int i = 0; i < 4; ++i)
        #pragma unroll
        for (int j = 0; j < 4; ++j)
            acc[i][j] = (f32x4){0.f, 0.f, 0.f, 0.f};

    for (int k0 = 0; k0 < ENC; k0 += 64) {
        __syncthreads();
        #pragma unroll
        for (int t = 0; t < 8; ++t)                  // A tile: 128 rows x 64 k fp32
            g2lds16(gA + (size_t)t * 16 * ENC + k0, ldsA + t * 4096);
        #pragma unroll
        for (int t = 0; t < 4; ++t)                  // B tile: 128 rows x 64 k bf16
            g2lds16(gB + (size_t)t * 32 * ENC + k0, ldsB + t * 4096);
        __syncthreads();

        #pragma unroll
        for (int u = 0; u < 2; ++u) {                // two k32 substeps
            bf16x8 bfrag[4];
            #pragma unroll
            for (int j = 0; j < 4; ++j) {
                int nrow = wn * 64 + j * 16 + l16;
                int p = (u * 4 + q) ^ (l16 & 7);
                bfrag[j] = *(const bf16x8*)((const char*)Bs + nrow * 128 + p * 16);
            }
            #pragma unroll
            for (int i = 0; i < 4; ++i) {
                int mrow = wm * 64 + i * 16 + l16;
                int p0 = (u * 8 + 2 * q) ^ l16;
                int p1 = (u * 8 + 2 * q + 1) ^ l16;
                f32x4 lo = *(const f32x4*)((const char*)As + mrow * 256 + p0 * 16);
                f32x4 hi = *(const f32x4*)((const char*)As + mrow * 256 + p1 * 16);
                bf16x8 afrag = cvt8(lo, hi);
                #pragma unroll
                for (int j = 0; j < 4; ++j)
                    acc[i][j] = __builtin_amdgcn_mfma_f32_16x16x32_bf16(afrag, bfrag[j], acc[i][j], 0, 0, 0);
            }
        }
    }

    // epilogue: +bias +pos +view_embed, scatter rows to out[b, t, :]
    #pragma unroll
    for (int j = 0; j < 4; ++j) {
        int gcol = n0 + wn * 64 + j * 16 + l16;
        float bc = bias[gcol];
        float v0 = ve[gcol];
        float v1 = ve[DEC + gcol];
        #pragma unroll
        for (int i = 0; i < 4; ++i) {
            #pragma unroll
            for (int r = 0; r < 4; ++r) {
                int rl = wm * 64 + i * 16 + q * 4 + r;
                int t = rowt[rl];
                float val = acc[i][j][r] + bc + pos[(size_t)t * DEC + gcol]
                          + (t >= TOK ? v1 : v0);
                out[(size_t)rowdst[rl] * DEC + gcol] = val;
            }
        }
    }
}

extern "C" void kernel_launch(void* const* d_in, const int* in_sizes, int n_in,
                              void* d_out, int out_size, void* d_ws, size_t ws_size,
                              hipStream_t stream) {
    (void)in_sizes; (void)n_in; (void)out_size; (void)ws_size;
    const float* x    = (const float*)d_in[0];
    const int*   mids = (const int*)d_in[1];
    const float* W    = (const float*)d_in[2];
    const float* bias = (const float*)d_in[3];
    const float* mt   = (const float*)d_in[4];
    const float* pos  = (const float*)d_in[5];
    const float* ve   = (const float*)d_in[6];
    float* out = (float*)d_out;

    // workspace: W bf16 (1 MB) + maps
    unsigned short* wbm = (unsigned short*)d_ws;                     // DEC*ENC bf16
    int* visids = (int*)(wbm + (size_t)DEC * ENC);                   // B*V int
    unsigned char* flags = (unsigned char*)(visids + BATCH * VIS);   // B*392 bytes

    int n4w = DEC * ENC / 4;
    hipLaunchKernelGGL(cvt_bf16, dim3((n4w + 255) / 256), dim3(256), 0, stream, W, wbm, n4w);
    hipLaunchKernelGGL(build_map, dim3(BATCH), dim3(512), 0, stream, mids, visids, flags);
    hipLaunchKernelGGL(fill_masked, dim3(TOK2 * 128 / 256, BATCH), dim3(256), 0, stream,
                       flags, mt, pos, ve, out);
    hipLaunchKernelGGL(gemm_scatter, dim3(4, (BATCH * VIS) / 128), dim3(256), 0, stream,
                       x, wbm, bias, pos, ve, visids, out);
}